// Round 1
// baseline (224.035 us; speedup 1.0000x reference)
//
#include <hip/hip_runtime.h>

// GraphRelativeError: rel = |pred-target|/(|target|+0.1); per-graph mean over
// sorted segments (G=1024); output = mean(graph_means) * 10000  (1 fp32).
//
// Strategy: batch is SORTED with ~N/G=16384 elems/segment. A block of 8192
// contiguous elements spans at most 2 segments (w.h.p.). So we never stream
// the batch array: each block reads batch[s], batch[e-1]; equal -> one bin,
// differ by 1 -> binary search for the split (uniform broadcast loads, count
// derived from split index). Generic multi-boundary fallback kept for
// correctness but never taken for this data. Traffic: 128 MiB (pred+target)
// instead of 192-256 MiB.

#define EPSILON_F 0.1f
#define SCALE_F 10000.0f

constexpr int BLOCK = 256;
constexpr int EPB = 8192;              // elements per block
constexpr int IT = EPB / (BLOCK * 4);  // 8 float4 iterations per thread

// batch may be int32 (jax default) or int64 (if x64 enabled). Probe on device.
__device__ __forceinline__ int load_batch(const int* __restrict__ b32,
                                          long long idx, bool is64) {
  return b32[is64 ? (idx << 1) : idx];
}

__global__ __launch_bounds__(BLOCK)
void gre_seg(const float* __restrict__ pred, const float* __restrict__ target,
             const int* __restrict__ batch32, int n,
             float* __restrict__ sums, float* __restrict__ cnts) {
  const int tid = threadIdx.x;
  const long long s = (long long)blockIdx.x * EPB;
  long long e = s + EPB;
  if (e > n) e = n;

  // int64 storage <=> hi-word of last (max, =G-1 != 0) element is 0.
  const bool is64 = (batch32[n - 1] == 0);

  // ---- Phase 1: stream pred/target as float4, compute rel, hold in regs ----
  float r[IT][4];
  #pragma unroll
  for (int it = 0; it < IT; ++it) {
    long long i4 = s + (long long)(it * BLOCK + tid) * 4;
    if (i4 + 4 <= e) {
      float4 p4 = *reinterpret_cast<const float4*>(pred + i4);
      float4 t4 = *reinterpret_cast<const float4*>(target + i4);
      r[it][0] = fabsf(p4.x - t4.x) / (fabsf(t4.x) + EPSILON_F);
      r[it][1] = fabsf(p4.y - t4.y) / (fabsf(t4.y) + EPSILON_F);
      r[it][2] = fabsf(p4.z - t4.z) / (fabsf(t4.z) + EPSILON_F);
      r[it][3] = fabsf(p4.w - t4.w) / (fabsf(t4.w) + EPSILON_F);
    } else {
      #pragma unroll
      for (int j = 0; j < 4; ++j) {
        long long i = i4 + j;
        r[it][j] = (i < e)
            ? fabsf(pred[i] - target[i]) / (fabsf(target[i]) + EPSILON_F)
            : 0.f;
      }
    }
  }

  // ---- Phase 2: segment ids at block ends (uniform -> broadcast loads) ----
  const int b0 = load_batch(batch32, s, is64);
  const int b1 = load_batch(batch32, e - 1, is64);

  float A = 0.f, B = 0.f;
  long long p = e;  // split: [s,p) -> b0, [p,e) -> b1
  bool fast = true;

  if (b0 == b1) {
    #pragma unroll
    for (int it = 0; it < IT; ++it)
      #pragma unroll
      for (int j = 0; j < 4; ++j) A += r[it][j];
  } else if (b1 == b0 + 1) {
    // one boundary inside the block: binary search (uniform address chain)
    long long lo = s, hi = e - 1;
    while (hi - lo > 1) {
      long long mid = (lo + hi) >> 1;
      if (load_batch(batch32, mid, is64) > b0) hi = mid; else lo = mid;
    }
    p = hi;
    #pragma unroll
    for (int it = 0; it < IT; ++it) {
      long long i4 = s + (long long)(it * BLOCK + tid) * 4;
      #pragma unroll
      for (int j = 0; j < 4; ++j) {
        if (i4 + j < p) A += r[it][j]; else B += r[it][j];
      }
    }
  } else {
    // >=2 boundaries in one 8192-block: essentially impossible for this data
    // (segment sizes 16384 +/- ~128) but kept for correctness.
    fast = false;
    #pragma unroll
    for (int it = 0; it < IT; ++it) {
      long long i4 = s + (long long)(it * BLOCK + tid) * 4;
      for (int j = 0; j < 4; ++j) {
        long long i = i4 + j;
        if (i < e) {
          int gi = load_batch(batch32, i, is64);
          atomicAdd(&sums[gi], r[it][j]);
          atomicAdd(&cnts[gi], 1.f);
        }
      }
    }
  }

  if (fast) {
    // wave reduction, then one global atomic per wave per bin
    #pragma unroll
    for (int off = 32; off > 0; off >>= 1) {
      A += __shfl_down(A, off, 64);
      B += __shfl_down(B, off, 64);
    }
    if ((tid & 63) == 0) {
      atomicAdd(&sums[b0], A);
      if (b1 != b0) atomicAdd(&sums[b1], B);
    }
    if (tid == 0) {
      if (b0 == b1) {
        atomicAdd(&cnts[b0], (float)(e - s));
      } else {
        atomicAdd(&cnts[b0], (float)(p - s));
        atomicAdd(&cnts[b1], (float)(e - p));
      }
    }
  }
}

__global__ __launch_bounds__(64)
void gre_final(const float* __restrict__ sums, const float* __restrict__ cnts,
               float* __restrict__ out, int g) {
  const int tid = threadIdx.x;
  float v = 0.f;
  for (int i = tid; i < g; i += 64) v += sums[i] / cnts[i];
  #pragma unroll
  for (int off = 32; off > 0; off >>= 1) v += __shfl_down(v, off, 64);
  if (tid == 0) out[0] = (v / (float)g) * SCALE_F;
}

extern "C" void kernel_launch(void* const* d_in, const int* in_sizes, int n_in,
                              void* d_out, int out_size, void* d_ws, size_t ws_size,
                              hipStream_t stream) {
  const float* pred   = (const float*)d_in[0];
  const float* target = (const float*)d_in[1];
  const int*   batch  = (const int*)d_in[2];  // int32 or int64 storage; probed on device
  const int n = in_sizes[0];
  const int g = 1024;  // reference G (num_graphs lives on device; constant in reference)

  float* sums = (float*)d_ws;
  float* cnts = sums + g;
  hipMemsetAsync(d_ws, 0, 2 * g * sizeof(float), stream);  // graph-capturable

  const int nblocks = (n + EPB - 1) / EPB;
  gre_seg<<<nblocks, BLOCK, 0, stream>>>(pred, target, batch, n, sums, cnts);
  gre_final<<<1, 64, 0, stream>>>(sums, cnts, (float*)d_out, g);
}